// Round 15
// baseline (157.790 us; speedup 1.0000x reference)
//
#include <hip/hip_runtime.h>

typedef _Float16 f16x8 __attribute__((ext_vector_type(8)));
typedef __attribute__((ext_vector_type(4))) float f32x4;
typedef unsigned short u16;

__device__ __forceinline__ u16 f2h(float f) {
    _Float16 h = (_Float16)f;
    return __builtin_bit_cast(u16, h);
}

__device__ __forceinline__ f16x8 cvt8(float4 a, float4 b) {
    f16x8 r;
    r[0] = (_Float16)a.x; r[1] = (_Float16)a.y; r[2] = (_Float16)a.z; r[3] = (_Float16)a.w;
    r[4] = (_Float16)b.x; r[5] = (_Float16)b.y; r[6] = (_Float16)b.z; r[7] = (_Float16)b.w;
    return r;
}

// raw barrier: ds_writes must be visible (lgkmcnt), but register global-loads
// may stay in flight (NO vmcnt drain — that's the whole point vs __syncthreads)
#define LGKM0_BAR()                                                            \
    do {                                                                       \
        asm volatile("s_waitcnt lgkmcnt(0)" ::: "memory");                     \
        __builtin_amdgcn_s_barrier();                                          \
    } while (0)

// ---------------------------------------------------------------------------
// NT GEMM with fused fp32->fp16 staging (r13 structure, unchanged):
// 128x64 tile, BK=64, 4 waves (2x2 of 64x32, acc 4x2), mfma_f32_16x16x32_f16.
// Reg-staged double-buffered pipeline, raw s_barrier + lgkmcnt(0) only.
// LDS rows 128B (8x16B slots), XOR swizzle slot = cg ^ (row&7) on the write
// side, same XOR on read (0-conflict, measured r4/r7).
// ---------------------------------------------------------------------------
template<bool AF32, bool BF32, int OUT, bool BIAS, bool TW, int GX, int GY>
__global__ __launch_bounds__(256, 3)
void gemm_nt(const void* __restrict__ Av, const void* __restrict__ Bv,
             const float* __restrict__ bias,
             void* __restrict__ Cv, u16* __restrict__ CT,
             int K, int lda, int ldb, int ldc,
             long sA, long sB, long sC)
{
    __shared__ u16 lds[24576];   // 48KB = 2 buffers x 24KB
    constexpr int BOF  = 8192;
    constexpr int BUFE = 12288;

    const unsigned flat = blockIdx.x;
    const unsigned cpx  = gridDim.x >> 3;
    const unsigned id   = (flat & 7u) * cpx + (flat >> 3);
    const int bz  = (int)(id / (unsigned)(GX * GY));
    const int rem = (int)(id - (unsigned)bz * (GX * GY));
    const int by  = rem / GX;
    const int bx  = rem - by * GX;

    const int tid  = threadIdx.x;
    const int lane = tid & 63;
    const int wid  = tid >> 6;
    const int m0 = by * 128;
    const int n0 = bx * 64;

    const int rowS = tid >> 3;
    const int cg   = tid & 7;
    const int slw  = cg ^ (rowS & 7);

    const float* aF = nullptr; const u16* aH = nullptr;
    const float* bF = nullptr; const u16* bH = nullptr;
    if constexpr (AF32)
        aF = (const float*)Av + (size_t)bz * sA + ((size_t)(m0 + rowS)) * lda + cg * 8;
    else
        aH = (const u16*)Av + (size_t)bz * sA + ((size_t)(m0 + rowS)) * lda + cg * 8;
    if constexpr (BF32)
        bF = (const float*)Bv + (size_t)bz * sB + ((size_t)(n0 + rowS)) * ldb + cg * 8;
    else
        bH = (const u16*)Bv + (size_t)bz * sB + ((size_t)(n0 + rowS)) * ldb + cg * 8;

    const int wm = (wid & 1) * 64;
    const int wn = (wid >> 1) * 32;
    const int fr = lane & 15;
    const int fq = lane >> 4;

    f32x4 acc[4][2] = {};

    float4 rA[8]; f16x8 hA[4];
    float4 rB[4]; f16x8 hB[2];

    auto loadT = [&](int k0) {
        if constexpr (AF32) {
#pragma unroll
            for (int c = 0; c < 4; ++c) {
                const float* p = aF + (size_t)(c * 32) * lda + k0;
                rA[2 * c]     = *(const float4*)p;
                rA[2 * c + 1] = *(const float4*)(p + 4);
            }
        } else {
#pragma unroll
            for (int c = 0; c < 4; ++c)
                hA[c] = *(const f16x8*)(aH + (size_t)(c * 32) * lda + k0);
        }
        if constexpr (BF32) {
#pragma unroll
            for (int c = 0; c < 2; ++c) {
                const float* p = bF + (size_t)(c * 32) * ldb + k0;
                rB[2 * c]     = *(const float4*)p;
                rB[2 * c + 1] = *(const float4*)(p + 4);
            }
        } else {
#pragma unroll
            for (int c = 0; c < 2; ++c)
                hB[c] = *(const f16x8*)(bH + (size_t)(c * 32) * ldb + k0);
        }
    };

    auto writeT = [&](int be) {
#pragma unroll
        for (int c = 0; c < 4; ++c) {
            f16x8 v;
            if constexpr (AF32) v = cvt8(rA[2 * c], rA[2 * c + 1]);
            else                v = hA[c];
            *(f16x8*)(lds + be + (c * 32 + rowS) * 64 + slw * 8) = v;
        }
#pragma unroll
        for (int c = 0; c < 2; ++c) {
            f16x8 v;
            if constexpr (BF32) v = cvt8(rB[2 * c], rB[2 * c + 1]);
            else                v = hB[c];
            *(f16x8*)(lds + be + BOF + (c * 32 + rowS) * 64 + slw * 8) = v;
        }
    };

    auto compute = [&](int be) {
#pragma unroll
        for (int w = 0; w < 2; ++w) {
            const int sw = (((w << 2) | fq) ^ (fr & 7)) << 3;
            f16x8 vah[4], vbh[2];
#pragma unroll
            for (int i = 0; i < 4; ++i)
                vah[i] = *(const f16x8*)(lds + be + (wm + i * 16 + fr) * 64 + sw);
#pragma unroll
            for (int j = 0; j < 2; ++j)
                vbh[j] = *(const f16x8*)(lds + be + BOF + (wn + j * 16 + fr) * 64 + sw);
#pragma unroll
            for (int i = 0; i < 4; ++i)
#pragma unroll
                for (int j = 0; j < 2; ++j)
                    acc[i][j] = __builtin_amdgcn_mfma_f32_16x16x32_f16(vah[i], vbh[j], acc[i][j], 0, 0, 0);
        }
    };

    loadT(0);
    writeT(0);
    loadT(64);
    LGKM0_BAR();
    for (int k0 = 0; k0 < K; k0 += 128) {
        compute(0);
        writeT(BUFE);
        if (k0 + 128 < K) loadT(k0 + 128);
        LGKM0_BAR();
        compute(BUFE);
        if (k0 + 128 < K) {
            writeT(0);
            if (k0 + 192 < K) loadT(k0 + 192);
        }
        LGKM0_BAR();
    }

    float bj[2];
    if (BIAS) {
#pragma unroll
        for (int j = 0; j < 2; ++j) bj[j] = bias[n0 + wn + j * 16 + fr];
    }
    const long crow0 = m0 + wm + fq * 4;
    const long ccol0 = n0 + wn + fr;
    float* Cf = (float*)Cv + (size_t)bz * sC;
    u16*   Ch = (u16*)Cv   + (size_t)bz * sC;
    const int  bzT = (int)(crow0 >> 9);
    const long qb  = crow0 & 511;
#pragma unroll
    for (int i = 0; i < 4; ++i)
#pragma unroll
        for (int j = 0; j < 2; ++j) {
            ushort4 tw;
#pragma unroll
            for (int r = 0; r < 4; ++r) {
                float v = acc[i][j][r];
                if (BIAS) v += bj[j];
                const size_t idx = (size_t)(crow0 + i * 16 + r) * ldc + ccol0 + j * 16;
                if (OUT == 0) Cf[idx] = v;
                else {
                    const u16 h = f2h(v);
                    Ch[idx] = h;
                    if (TW) (&tw.x)[r] = h;
                }
            }
            if (OUT == 1 && TW) {
                *(ushort4*)(CT + (size_t)bzT * 768 * 512
                               + (size_t)(ccol0 + j * 16) * 512 + qb + i * 16) = tw;
            }
        }
}

// ---------------------------------------------------------------------------
// Fused PV GEMM: out = relu(probs @ tqT^T + bias*(1-rs)), with the MedLane
// masked softmax computed IN-KERNEL from raw att fp32.
//   pass 1: row max M over masked scores (streamed, L2-hot)
//   pass 2: sve = sum exp(v-M) over valid, NO store
//           Z = sve + (512-L)e^{-M} (analytic tail, r11-validated);
//           sc = 1/((S+1e-13)Z); rs via 512B LDS.
//   pass 3: P = fp16(exp(v-M) * sc) stored in VGPRs (32 x f16x8 = 128 VGPR)
//           — SINGLE fp16 rounding of the final prob (r14's double-rounding
//           of unscaled exp overflowed the error budget: 0.1016 > 0.0988).
//   K-loop: 8 steps fully unrolled (K=512); A staged straight from P regs,
//           only B (tqT) reg-staged from global.
// Same LDS geometry / barrier discipline / swizzle as gemm_nt.
// ---------------------------------------------------------------------------
template<int GX, int GY>
__global__ __launch_bounds__(256, 2)
void gemm_pv_sm(const float* __restrict__ att, const u16* __restrict__ tqT,
                const float* __restrict__ bias, const int* __restrict__ seq_len,
                float* __restrict__ out)
{
    __shared__ u16 lds[24576];
    __shared__ float rs_l[128];
    constexpr int BOF  = 8192;
    constexpr int BUFE = 12288;

    const unsigned flat = blockIdx.x;
    const unsigned cpx  = gridDim.x >> 3;
    const unsigned id   = (flat & 7u) * cpx + (flat >> 3);
    const int bz  = (int)(id / (unsigned)(GX * GY));
    const int rem = (int)(id - (unsigned)bz * (GX * GY));
    const int by  = rem / GX;
    const int bx  = rem - by * GX;

    const int tid  = threadIdx.x;
    const int lane = tid & 63;
    const int wid  = tid >> 6;
    const int m0 = by * 128;
    const int n0 = bx * 64;

    const int rowS = tid >> 3;
    const int cg   = tid & 7;
    const int slw  = cg ^ (rowS & 7);
    const int L    = seq_len[bz];

    const float* aP = att + (size_t)bz * 512 * 512 + (size_t)(m0 + rowS) * 512 + cg * 8;
    const u16*   bP = tqT + (size_t)bz * 768 * 512 + (size_t)(n0 + rowS) * 512 + cg * 8;

    // ---- pass 1: row max of masked scores (s = att*mask, zeros included)
    float mr[4] = {-INFINITY, -INFINITY, -INFINITY, -INFINITY};
#pragma unroll
    for (int c = 0; c < 4; ++c)
#pragma unroll
        for (int st = 0; st < 8; ++st) {
            const float* p = aP + (size_t)(c * 32) * 512 + st * 64;
            float4 a0 = *(const float4*)p;
            float4 a1 = *(const float4*)(p + 4);
            const int q0 = st * 64 + cg * 8;
#pragma unroll
            for (int e = 0; e < 8; ++e) {
                const float x = e < 4 ? (&a0.x)[e] : (&a1.x)[e - 4];
                mr[c] = fmaxf(mr[c], (q0 + e < L) ? x : 0.0f);
            }
        }
#pragma unroll
    for (int c = 0; c < 4; ++c) {
        mr[c] = fmaxf(mr[c], __shfl_xor(mr[c], 1));
        mr[c] = fmaxf(mr[c], __shfl_xor(mr[c], 2));
        mr[c] = fmaxf(mr[c], __shfl_xor(mr[c], 4));
    }

    // ---- pass 2: sve = sum exp(v - M) over valid (no store)
    float zr[4] = {};
#pragma unroll
    for (int c = 0; c < 4; ++c)
#pragma unroll
        for (int st = 0; st < 8; ++st) {
            const float* p = aP + (size_t)(c * 32) * 512 + st * 64;
            float4 a0 = *(const float4*)p;
            float4 a1 = *(const float4*)(p + 4);
            const int q0 = st * 64 + cg * 8;
#pragma unroll
            for (int e = 0; e < 8; ++e) {
                const float x = e < 4 ? (&a0.x)[e] : (&a1.x)[e - 4];
                zr[c] += (q0 + e < L) ? __expf(x - mr[c]) : 0.0f;
            }
        }

    float sc_c[4];
#pragma unroll
    for (int c = 0; c < 4; ++c) {
        zr[c] += __shfl_xor(zr[c], 1);
        zr[c] += __shfl_xor(zr[c], 2);
        zr[c] += __shfl_xor(zr[c], 4);
        const float Z   = zr[c] + (float)(512 - L) * __expf(-mr[c]);
        const float S   = zr[c] / Z;
        const float inv = 1.0f / (S + 1e-13f);
        sc_c[c] = inv / Z;
        if (cg == 0) rs_l[c * 32 + rowS] = S * inv;
    }

    // ---- pass 3: P = fp16(exp(v - M) * sc) — single rounding (L2-hot reread)
    f16x8 P[4][8];
#pragma unroll
    for (int c = 0; c < 4; ++c)
#pragma unroll
        for (int st = 0; st < 8; ++st) {
            const float* p = aP + (size_t)(c * 32) * 512 + st * 64;
            float4 a0 = *(const float4*)p;
            float4 a1 = *(const float4*)(p + 4);
            const int q0 = st * 64 + cg * 8;
            f16x8 ph;
#pragma unroll
            for (int e = 0; e < 8; ++e) {
                const float x = e < 4 ? (&a0.x)[e] : (&a1.x)[e - 4];
                const float pe = (q0 + e < L) ? __expf(x - mr[c]) * sc_c[c] : 0.0f;
                ph[e] = (_Float16)pe;
            }
            P[c][st] = ph;
        }

    const int wm = (wid & 1) * 64;
    const int wn = (wid >> 1) * 32;
    const int fr = lane & 15;
    const int fq = lane >> 4;

    f32x4 acc[4][2] = {};
    f16x8 hB0[2], hB1[2];

    auto loadB = [&](int st, bool set1) {
        f16x8* h = set1 ? hB1 : hB0;
#pragma unroll
        for (int c = 0; c < 2; ++c)
            h[c] = *(const f16x8*)(bP + (size_t)(c * 32) * 512 + st * 64);
    };
    auto writeT = [&](int be, int st, bool set1) {
        const f16x8* h = set1 ? hB1 : hB0;
#pragma unroll
        for (int c = 0; c < 4; ++c)
            *(f16x8*)(lds + be + (c * 32 + rowS) * 64 + slw * 8) = P[c][st];
#pragma unroll
        for (int c = 0; c < 2; ++c)
            *(f16x8*)(lds + be + BOF + (c * 32 + rowS) * 64 + slw * 8) = h[c];
    };
    auto compute = [&](int be) {
#pragma unroll
        for (int w = 0; w < 2; ++w) {
            const int sw = (((w << 2) | fq) ^ (fr & 7)) << 3;
            f16x8 vah[4], vbh[2];
#pragma unroll
            for (int i = 0; i < 4; ++i)
                vah[i] = *(const f16x8*)(lds + be + (wm + i * 16 + fr) * 64 + sw);
#pragma unroll
            for (int j = 0; j < 2; ++j)
                vbh[j] = *(const f16x8*)(lds + be + BOF + (wn + j * 16 + fr) * 64 + sw);
#pragma unroll
            for (int i = 0; i < 4; ++i)
#pragma unroll
                for (int j = 0; j < 2; ++j)
                    acc[i][j] = __builtin_amdgcn_mfma_f32_16x16x32_f16(vah[i], vbh[j], acc[i][j], 0, 0, 0);
        }
    };

    // ---- K-loop, 8 steps of BK=64, fully unrolled (P indices compile-time)
    loadB(0, false);
    writeT(0, 0, false);
    loadB(1, true);
    LGKM0_BAR();
#pragma unroll
    for (int st = 0; st < 8; ++st) {
        compute((st & 1) ? BUFE : 0);
        if (st < 7) writeT((st & 1) ? 0 : BUFE, st + 1, !(st & 1));
        if (st < 6) loadB(st + 2, (st & 1) != 0);
        LGKM0_BAR();
    }

    float bj[2];
#pragma unroll
    for (int j = 0; j < 2; ++j) bj[j] = bias[n0 + wn + j * 16 + fr];
    const int  lr0   = wm + fq * 4;
    const long crow0 = m0 + lr0;
    const long ccol0 = n0 + wn + fr;
    float* op = out + (size_t)bz * 512 * 768;
#pragma unroll
    for (int i = 0; i < 4; ++i)
#pragma unroll
        for (int j = 0; j < 2; ++j)
#pragma unroll
            for (int r = 0; r < 4; ++r) {
                float v = acc[i][j][r] + bj[j] * (1.0f - rs_l[lr0 + i * 16 + r]);
                v = fmaxf(v, 0.0f);
                op[(size_t)(crow0 + i * 16 + r) * 768 + ccol0 + j * 16] = v;
            }
}

extern "C" void kernel_launch(void* const* d_in, const int* in_sizes, int n_in,
                              void* d_out, int out_size, void* d_ws, size_t ws_size,
                              hipStream_t stream)
{
    (void)in_sizes; (void)n_in; (void)out_size; (void)ws_size;
    constexpr int B = 16, L = 512, H = 768;
    constexpr size_t NPQ = (size_t)B * L * H;   // 6291456

    const float* proj_p  = (const float*)d_in[0];
    const float* proj_q  = (const float*)d_in[1];
    const int*   seq_len = (const int*)d_in[2];
    const float* W       = (const float*)d_in[3];
    const float* bias    = (const float*)d_in[4];
    float* out = (float*)d_out;

    // workspace (u16 elements): tqT | att
    u16* ws   = (u16*)d_ws;
    u16* tqT  = ws;                    // [B,768,512] fp16 (trans_q transposed)
    float* att = (float*)(tqT + NPQ);  // [B,512,512] fp32 raw scores

    // trans_q fp16 lives in d_out's first half (dead before final GEMM writes)
    u16* tq16 = (u16*)d_out;

    // 1) tq16 = pq @ W^T + bias  (fp32 sources, cvt fused in staging;
    //    fp16 out, dual row-major + transposed write)  grid 12x64 = 768
    gemm_nt<true, true, 1, true, true, 12, 64><<<768, 256, 0, stream>>>(
        proj_q, W, bias, tq16, tqT, H, H, H, H, 0, 0, 0);

    // 2) att[b] = pp[b] @ tq[b]^T  (pp fp32 cvt-fused, tq fp16; fp32 out)
    //    grid 8x4x16 = 512
    gemm_nt<true, false, 0, false, false, 8, 4><<<512, 256, 0, stream>>>(
        proj_p, tq16, nullptr, att, nullptr, H, H, H, L,
        (long)L * H, (long)L * H, (long)L * L);

    // 3) out = relu(softmax_masked(att) @ tqT^T + bias*(1-rs))
    //    softmax fused in-kernel (3-pass, single-rounded P).  grid 12x4x16 = 768
    gemm_pv_sm<12, 4><<<768, 256, 0, stream>>>(att, tqT, bias, seq_len, out);
}

// Round 16
// 126.975 us; speedup vs baseline: 1.2427x; 1.2427x over previous
//
#include <hip/hip_runtime.h>

typedef _Float16 f16x8 __attribute__((ext_vector_type(8)));
typedef __attribute__((ext_vector_type(4))) float f32x4;
typedef unsigned short u16;

__device__ __forceinline__ u16 f2h(float f) {
    _Float16 h = (_Float16)f;
    return __builtin_bit_cast(u16, h);
}

__device__ __forceinline__ f16x8 cvt8(float4 a, float4 b) {
    f16x8 r;
    r[0] = (_Float16)a.x; r[1] = (_Float16)a.y; r[2] = (_Float16)a.z; r[3] = (_Float16)a.w;
    r[4] = (_Float16)b.x; r[5] = (_Float16)b.y; r[6] = (_Float16)b.z; r[7] = (_Float16)b.w;
    return r;
}

// raw barrier: ds_writes must be visible (lgkmcnt), but register global-loads
// may stay in flight (NO vmcnt drain — that's the whole point vs __syncthreads)
#define LGKM0_BAR()                                                            \
    do {                                                                       \
        asm volatile("s_waitcnt lgkmcnt(0)" ::: "memory");                     \
        __builtin_amdgcn_s_barrier();                                          \
    } while (0)

// ---------------------------------------------------------------------------
// NT GEMM with fused fp32->fp16 staging (r13 structure, unchanged):
// 128x64 tile, BK=64, 4 waves (2x2 of 64x32, acc 4x2), mfma_f32_16x16x32_f16.
// Reg-staged double-buffered pipeline, raw s_barrier + lgkmcnt(0) only.
// LDS rows 128B (8x16B slots), XOR swizzle slot = cg ^ (row&7) on the write
// side, same XOR on read (0-conflict, measured r4/r7).
// ---------------------------------------------------------------------------
template<bool AF32, bool BF32, int OUT, bool BIAS, bool TW, int GX, int GY>
__global__ __launch_bounds__(256, 3)
void gemm_nt(const void* __restrict__ Av, const void* __restrict__ Bv,
             const float* __restrict__ bias,
             void* __restrict__ Cv, u16* __restrict__ CT,
             int K, int lda, int ldb, int ldc,
             long sA, long sB, long sC)
{
    __shared__ u16 lds[24576];   // 48KB = 2 buffers x 24KB
    constexpr int BOF  = 8192;
    constexpr int BUFE = 12288;

    const unsigned flat = blockIdx.x;
    const unsigned cpx  = gridDim.x >> 3;
    const unsigned id   = (flat & 7u) * cpx + (flat >> 3);
    const int bz  = (int)(id / (unsigned)(GX * GY));
    const int rem = (int)(id - (unsigned)bz * (GX * GY));
    const int by  = rem / GX;
    const int bx  = rem - by * GX;

    const int tid  = threadIdx.x;
    const int lane = tid & 63;
    const int wid  = tid >> 6;
    const int m0 = by * 128;
    const int n0 = bx * 64;

    const int rowS = tid >> 3;
    const int cg   = tid & 7;
    const int slw  = cg ^ (rowS & 7);

    const float* aF = nullptr; const u16* aH = nullptr;
    const float* bF = nullptr; const u16* bH = nullptr;
    if constexpr (AF32)
        aF = (const float*)Av + (size_t)bz * sA + ((size_t)(m0 + rowS)) * lda + cg * 8;
    else
        aH = (const u16*)Av + (size_t)bz * sA + ((size_t)(m0 + rowS)) * lda + cg * 8;
    if constexpr (BF32)
        bF = (const float*)Bv + (size_t)bz * sB + ((size_t)(n0 + rowS)) * ldb + cg * 8;
    else
        bH = (const u16*)Bv + (size_t)bz * sB + ((size_t)(n0 + rowS)) * ldb + cg * 8;

    const int wm = (wid & 1) * 64;
    const int wn = (wid >> 1) * 32;
    const int fr = lane & 15;
    const int fq = lane >> 4;

    f32x4 acc[4][2] = {};

    float4 rA[8]; f16x8 hA[4];
    float4 rB[4]; f16x8 hB[2];

    auto loadT = [&](int k0) {
        if constexpr (AF32) {
#pragma unroll
            for (int c = 0; c < 4; ++c) {
                const float* p = aF + (size_t)(c * 32) * lda + k0;
                rA[2 * c]     = *(const float4*)p;
                rA[2 * c + 1] = *(const float4*)(p + 4);
            }
        } else {
#pragma unroll
            for (int c = 0; c < 4; ++c)
                hA[c] = *(const f16x8*)(aH + (size_t)(c * 32) * lda + k0);
        }
        if constexpr (BF32) {
#pragma unroll
            for (int c = 0; c < 2; ++c) {
                const float* p = bF + (size_t)(c * 32) * ldb + k0;
                rB[2 * c]     = *(const float4*)p;
                rB[2 * c + 1] = *(const float4*)(p + 4);
            }
        } else {
#pragma unroll
            for (int c = 0; c < 2; ++c)
                hB[c] = *(const f16x8*)(bH + (size_t)(c * 32) * ldb + k0);
        }
    };

    auto writeT = [&](int be) {
#pragma unroll
        for (int c = 0; c < 4; ++c) {
            f16x8 v;
            if constexpr (AF32) v = cvt8(rA[2 * c], rA[2 * c + 1]);
            else                v = hA[c];
            *(f16x8*)(lds + be + (c * 32 + rowS) * 64 + slw * 8) = v;
        }
#pragma unroll
        for (int c = 0; c < 2; ++c) {
            f16x8 v;
            if constexpr (BF32) v = cvt8(rB[2 * c], rB[2 * c + 1]);
            else                v = hB[c];
            *(f16x8*)(lds + be + BOF + (c * 32 + rowS) * 64 + slw * 8) = v;
        }
    };

    auto compute = [&](int be) {
#pragma unroll
        for (int w = 0; w < 2; ++w) {
            const int sw = (((w << 2) | fq) ^ (fr & 7)) << 3;
            f16x8 vah[4], vbh[2];
#pragma unroll
            for (int i = 0; i < 4; ++i)
                vah[i] = *(const f16x8*)(lds + be + (wm + i * 16 + fr) * 64 + sw);
#pragma unroll
            for (int j = 0; j < 2; ++j)
                vbh[j] = *(const f16x8*)(lds + be + BOF + (wn + j * 16 + fr) * 64 + sw);
#pragma unroll
            for (int i = 0; i < 4; ++i)
#pragma unroll
                for (int j = 0; j < 2; ++j)
                    acc[i][j] = __builtin_amdgcn_mfma_f32_16x16x32_f16(vah[i], vbh[j], acc[i][j], 0, 0, 0);
        }
    };

    loadT(0);
    writeT(0);
    loadT(64);
    LGKM0_BAR();
    for (int k0 = 0; k0 < K; k0 += 128) {
        compute(0);
        writeT(BUFE);
        if (k0 + 128 < K) loadT(k0 + 128);
        LGKM0_BAR();
        compute(BUFE);
        if (k0 + 128 < K) {
            writeT(0);
            if (k0 + 192 < K) loadT(k0 + 192);
        }
        LGKM0_BAR();
    }

    float bj[2];
    if (BIAS) {
#pragma unroll
        for (int j = 0; j < 2; ++j) bj[j] = bias[n0 + wn + j * 16 + fr];
    }
    const long crow0 = m0 + wm + fq * 4;
    const long ccol0 = n0 + wn + fr;
    float* Cf = (float*)Cv + (size_t)bz * sC;
    u16*   Ch = (u16*)Cv   + (size_t)bz * sC;
    const int  bzT = (int)(crow0 >> 9);
    const long qb  = crow0 & 511;
#pragma unroll
    for (int i = 0; i < 4; ++i)
#pragma unroll
        for (int j = 0; j < 2; ++j) {
            ushort4 tw;
#pragma unroll
            for (int r = 0; r < 4; ++r) {
                float v = acc[i][j][r];
                if (BIAS) v += bj[j];
                const size_t idx = (size_t)(crow0 + i * 16 + r) * ldc + ccol0 + j * 16;
                if (OUT == 0) Cf[idx] = v;
                else {
                    const u16 h = f2h(v);
                    Ch[idx] = h;
                    if (TW) (&tw.x)[r] = h;
                }
            }
            if (OUT == 1 && TW) {
                *(ushort4*)(CT + (size_t)bzT * 768 * 512
                               + (size_t)(ccol0 + j * 16) * 512 + qb + i * 16) = tw;
            }
        }
}

// ---------------------------------------------------------------------------
// Fused PV GEMM: out = relu(probs @ tqT^T + bias*(1-rs)), masked softmax
// computed IN-KERNEL from raw att fp32 — NO P cache (r15's 128-VGPR P array
// spilled to scratch: 113MB writes, 178µs). Instead exp is computed ON-STAGE:
//   pass 1: row max M over masked scores (streamed, L2-hot)
//   pass 2: sve = sum exp(v-M) over valid (no store);
//           Z = sve + (512-L)e^{-M} (analytic tail); sc = 1/((S+1e-13)Z);
//           rs via 512B LDS.
//   K-loop: r13 reg-staged pipeline; A-operand = att fp32 re-read (L2-hot),
//           transformed in writeT to fp16(exp(x-M)*sc) — SINGLE fp16
//           rounding (numerics proven r15: absmax 0.0625).
// Registers ≈ gemm_nt AF32 path (rA 32 + hB 8 + acc 32) -> no spill.
// ---------------------------------------------------------------------------
template<int GX, int GY>
__global__ __launch_bounds__(256, 3)
void gemm_pv_sm(const float* __restrict__ att, const u16* __restrict__ tqT,
                const float* __restrict__ bias, const int* __restrict__ seq_len,
                float* __restrict__ out)
{
    __shared__ u16 lds[24576];
    __shared__ float rs_l[128];
    constexpr int BOF  = 8192;
    constexpr int BUFE = 12288;

    const unsigned flat = blockIdx.x;
    const unsigned cpx  = gridDim.x >> 3;
    const unsigned id   = (flat & 7u) * cpx + (flat >> 3);
    const int bz  = (int)(id / (unsigned)(GX * GY));
    const int rem = (int)(id - (unsigned)bz * (GX * GY));
    const int by  = rem / GX;
    const int bx  = rem - by * GX;

    const int tid  = threadIdx.x;
    const int lane = tid & 63;
    const int wid  = tid >> 6;
    const int m0 = by * 128;
    const int n0 = bx * 64;

    const int rowS = tid >> 3;
    const int cg   = tid & 7;
    const int slw  = cg ^ (rowS & 7);
    const int L    = seq_len[bz];

    const float* aP = att + (size_t)bz * 512 * 512 + (size_t)(m0 + rowS) * 512 + cg * 8;
    const u16*   bP = tqT + (size_t)bz * 768 * 512 + (size_t)(n0 + rowS) * 512 + cg * 8;

    // ---- pass 1: row max of masked scores (s = att*mask, zeros included)
    float mr[4] = {-INFINITY, -INFINITY, -INFINITY, -INFINITY};
#pragma unroll
    for (int c = 0; c < 4; ++c)
        for (int st = 0; st < 8; ++st) {
            const float* p = aP + (size_t)(c * 32) * 512 + st * 64;
            float4 a0 = *(const float4*)p;
            float4 a1 = *(const float4*)(p + 4);
            const int q0 = st * 64 + cg * 8;
#pragma unroll
            for (int e = 0; e < 8; ++e) {
                const float x = e < 4 ? (&a0.x)[e] : (&a1.x)[e - 4];
                mr[c] = fmaxf(mr[c], (q0 + e < L) ? x : 0.0f);
            }
        }
#pragma unroll
    for (int c = 0; c < 4; ++c) {
        mr[c] = fmaxf(mr[c], __shfl_xor(mr[c], 1));
        mr[c] = fmaxf(mr[c], __shfl_xor(mr[c], 2));
        mr[c] = fmaxf(mr[c], __shfl_xor(mr[c], 4));
    }

    // ---- pass 2: sve = sum exp(v - M) over valid (no store)
    float zr[4] = {};
#pragma unroll
    for (int c = 0; c < 4; ++c)
        for (int st = 0; st < 8; ++st) {
            const float* p = aP + (size_t)(c * 32) * 512 + st * 64;
            float4 a0 = *(const float4*)p;
            float4 a1 = *(const float4*)(p + 4);
            const int q0 = st * 64 + cg * 8;
#pragma unroll
            for (int e = 0; e < 8; ++e) {
                const float x = e < 4 ? (&a0.x)[e] : (&a1.x)[e - 4];
                zr[c] += (q0 + e < L) ? __expf(x - mr[c]) : 0.0f;
            }
        }

    float sc_c[4];
#pragma unroll
    for (int c = 0; c < 4; ++c) {
        zr[c] += __shfl_xor(zr[c], 1);
        zr[c] += __shfl_xor(zr[c], 2);
        zr[c] += __shfl_xor(zr[c], 4);
        const float Z   = zr[c] + (float)(512 - L) * __expf(-mr[c]);
        const float S   = zr[c] / Z;
        const float inv = 1.0f / (S + 1e-13f);
        sc_c[c] = inv / Z;
        if (cg == 0) rs_l[c * 32 + rowS] = S * inv;
    }

    const int wm = (wid & 1) * 64;
    const int wn = (wid >> 1) * 32;
    const int fr = lane & 15;
    const int fq = lane >> 4;

    f32x4 acc[4][2] = {};
    float4 rA[8];
    f16x8  hB[2];

    auto loadT = [&](int k0) {   // A = att fp32, B = tqT fp16
#pragma unroll
        for (int c = 0; c < 4; ++c) {
            const float* p = aP + (size_t)(c * 32) * 512 + k0;
            rA[2 * c]     = *(const float4*)p;
            rA[2 * c + 1] = *(const float4*)(p + 4);
        }
#pragma unroll
        for (int c = 0; c < 2; ++c)
            hB[c] = *(const f16x8*)(bP + (size_t)(c * 32) * 512 + k0);
    };

    auto writeT = [&](int be, int k0) {  // P = fp16(exp(x-M)*sc), single round
        const int q0 = k0 + cg * 8;
#pragma unroll
        for (int c = 0; c < 4; ++c) {
            f16x8 v;
#pragma unroll
            for (int e = 0; e < 8; ++e) {
                const float x = e < 4 ? (&rA[2 * c].x)[e] : (&rA[2 * c + 1].x)[e - 4];
                const float pe = (q0 + e < L) ? __expf(x - mr[c]) * sc_c[c] : 0.0f;
                v[e] = (_Float16)pe;
            }
            *(f16x8*)(lds + be + (c * 32 + rowS) * 64 + slw * 8) = v;
        }
#pragma unroll
        for (int c = 0; c < 2; ++c)
            *(f16x8*)(lds + be + BOF + (c * 32 + rowS) * 64 + slw * 8) = hB[c];
    };

    auto compute = [&](int be) {
#pragma unroll
        for (int w = 0; w < 2; ++w) {
            const int sw = (((w << 2) | fq) ^ (fr & 7)) << 3;
            f16x8 vah[4], vbh[2];
#pragma unroll
            for (int i = 0; i < 4; ++i)
                vah[i] = *(const f16x8*)(lds + be + (wm + i * 16 + fr) * 64 + sw);
#pragma unroll
            for (int j = 0; j < 2; ++j)
                vbh[j] = *(const f16x8*)(lds + be + BOF + (wn + j * 16 + fr) * 64 + sw);
#pragma unroll
            for (int i = 0; i < 4; ++i)
#pragma unroll
                for (int j = 0; j < 2; ++j)
                    acc[i][j] = __builtin_amdgcn_mfma_f32_16x16x32_f16(vah[i], vbh[j], acc[i][j], 0, 0, 0);
        }
    };

    // ---- r13 reg-staged pipeline, K=512
    loadT(0);
    writeT(0, 0);
    loadT(64);
    LGKM0_BAR();
    for (int k0 = 0; k0 < 512; k0 += 128) {
        compute(0);
        writeT(BUFE, k0 + 64);
        if (k0 + 128 < 512) loadT(k0 + 128);
        LGKM0_BAR();
        compute(BUFE);
        if (k0 + 128 < 512) {
            writeT(0, k0 + 128);
            if (k0 + 192 < 512) loadT(k0 + 192);
        }
        LGKM0_BAR();
    }

    float bj[2];
#pragma unroll
    for (int j = 0; j < 2; ++j) bj[j] = bias[n0 + wn + j * 16 + fr];
    const int  lr0   = wm + fq * 4;
    const long crow0 = m0 + lr0;
    const long ccol0 = n0 + wn + fr;
    float* op = out + (size_t)bz * 512 * 768;
#pragma unroll
    for (int i = 0; i < 4; ++i)
#pragma unroll
        for (int j = 0; j < 2; ++j)
#pragma unroll
            for (int r = 0; r < 4; ++r) {
                float v = acc[i][j][r] + bj[j] * (1.0f - rs_l[lr0 + i * 16 + r]);
                v = fmaxf(v, 0.0f);
                op[(size_t)(crow0 + i * 16 + r) * 768 + ccol0 + j * 16] = v;
            }
}

extern "C" void kernel_launch(void* const* d_in, const int* in_sizes, int n_in,
                              void* d_out, int out_size, void* d_ws, size_t ws_size,
                              hipStream_t stream)
{
    (void)in_sizes; (void)n_in; (void)out_size; (void)ws_size;
    constexpr int B = 16, L = 512, H = 768;
    constexpr size_t NPQ = (size_t)B * L * H;   // 6291456

    const float* proj_p  = (const float*)d_in[0];
    const float* proj_q  = (const float*)d_in[1];
    const int*   seq_len = (const int*)d_in[2];
    const float* W       = (const float*)d_in[3];
    const float* bias    = (const float*)d_in[4];
    float* out = (float*)d_out;

    // workspace (u16 elements): tqT | att
    u16* ws   = (u16*)d_ws;
    u16* tqT  = ws;                    // [B,768,512] fp16 (trans_q transposed)
    float* att = (float*)(tqT + NPQ);  // [B,512,512] fp32 raw scores

    // trans_q fp16 lives in d_out's first half (dead before final GEMM writes)
    u16* tq16 = (u16*)d_out;

    // 1) tq16 = pq @ W^T + bias  (fp32 sources, cvt fused in staging;
    //    fp16 out, dual row-major + transposed write)  grid 12x64 = 768
    gemm_nt<true, true, 1, true, true, 12, 64><<<768, 256, 0, stream>>>(
        proj_q, W, bias, tq16, tqT, H, H, H, H, 0, 0, 0);

    // 2) att[b] = pp[b] @ tq[b]^T  (pp fp32 cvt-fused, tq fp16; fp32 out)
    //    grid 8x4x16 = 512
    gemm_nt<true, false, 0, false, false, 8, 4><<<512, 256, 0, stream>>>(
        proj_p, tq16, nullptr, att, nullptr, H, H, H, L,
        (long)L * H, (long)L * H, (long)L * L);

    // 3) out = relu(softmax_masked(att) @ tqT^T + bias*(1-rs))
    //    softmax fused, exp-on-stage (no P cache -> no spill).  grid 12x4x16 = 768
    gemm_pv_sm<12, 4><<<768, 256, 0, stream>>>(att, tqT, bias, seq_len, out);
}

// Round 17
// 68.267 us; speedup vs baseline: 2.3113x; 1.8600x over previous
//
#include <hip/hip_runtime.h>

typedef _Float16 f16x8 __attribute__((ext_vector_type(8)));
typedef __attribute__((ext_vector_type(4))) float f32x4;
typedef unsigned short u16;

__device__ __forceinline__ u16 f2h(float f) {
    _Float16 h = (_Float16)f;
    return __builtin_bit_cast(u16, h);
}

__device__ __forceinline__ f16x8 cvt8(float4 a, float4 b) {
    f16x8 r;
    r[0] = (_Float16)a.x; r[1] = (_Float16)a.y; r[2] = (_Float16)a.z; r[3] = (_Float16)a.w;
    r[4] = (_Float16)b.x; r[5] = (_Float16)b.y; r[6] = (_Float16)b.z; r[7] = (_Float16)b.w;
    return r;
}

// raw barrier: ds_writes must be visible (lgkmcnt), but register global-loads
// may stay in flight (NO vmcnt drain — that's the whole point vs __syncthreads)
#define LGKM0_BAR()                                                            \
    do {                                                                       \
        asm volatile("s_waitcnt lgkmcnt(0)" ::: "memory");                     \
        __builtin_amdgcn_s_barrier();                                          \
    } while (0)

// ---------------------------------------------------------------------------
// NT GEMM with fused fp32->fp16 staging (r13 structure — best measured):
// 128x64 tile, BK=64, 4 waves (2x2 of 64x32, acc 4x2), mfma_f32_16x16x32_f16.
// Reg-staged double-buffered pipeline, raw s_barrier + lgkmcnt(0) only.
// LDS rows 128B (8x16B slots), XOR swizzle slot = cg ^ (row&7) on the write
// side, same XOR on read (0-conflict, measured r4/r7).
// NOTE (r14-r16 lesson): do NOT fuse the softmax into the PV GEMM — caching
// P in VGPRs (128 regs) spills to scratch (113-128MB writes, MfmaUtil 2%),
// and exp-on-stage variants generate uncachable att re-read traffic. The
// separate softmax dispatch is cheaper than either.
// ---------------------------------------------------------------------------
template<bool AF32, bool BF32, int OUT, bool BIAS, bool RELU, bool RS, bool TW,
         int GX, int GY>
__global__ __launch_bounds__(256, 3)
void gemm_nt(const void* __restrict__ Av, const void* __restrict__ Bv,
             const float* __restrict__ bias, const float* __restrict__ rs,
             void* __restrict__ Cv, u16* __restrict__ CT,
             int K, int lda, int ldb, int ldc,
             long sA, long sB, long sC)
{
    __shared__ u16 lds[24576];   // 48KB = 2 buffers x 24KB
    constexpr int BOF  = 8192;
    constexpr int BUFE = 12288;

    const unsigned flat = blockIdx.x;
    const unsigned cpx  = gridDim.x >> 3;
    const unsigned id   = (flat & 7u) * cpx + (flat >> 3);
    const int bz  = (int)(id / (unsigned)(GX * GY));
    const int rem = (int)(id - (unsigned)bz * (GX * GY));
    const int by  = rem / GX;
    const int bx  = rem - by * GX;

    const int tid  = threadIdx.x;
    const int lane = tid & 63;
    const int wid  = tid >> 6;
    const int m0 = by * 128;
    const int n0 = bx * 64;

    const int rowS = tid >> 3;
    const int cg   = tid & 7;
    const int slw  = cg ^ (rowS & 7);

    const float* aF = nullptr; const u16* aH = nullptr;
    const float* bF = nullptr; const u16* bH = nullptr;
    if constexpr (AF32)
        aF = (const float*)Av + (size_t)bz * sA + ((size_t)(m0 + rowS)) * lda + cg * 8;
    else
        aH = (const u16*)Av + (size_t)bz * sA + ((size_t)(m0 + rowS)) * lda + cg * 8;
    if constexpr (BF32)
        bF = (const float*)Bv + (size_t)bz * sB + ((size_t)(n0 + rowS)) * ldb + cg * 8;
    else
        bH = (const u16*)Bv + (size_t)bz * sB + ((size_t)(n0 + rowS)) * ldb + cg * 8;

    const int wm = (wid & 1) * 64;
    const int wn = (wid >> 1) * 32;
    const int fr = lane & 15;
    const int fq = lane >> 4;

    f32x4 acc[4][2] = {};

    float4 rA[8]; f16x8 hA[4];
    float4 rB[4]; f16x8 hB[2];

    auto loadT = [&](int k0) {
        if constexpr (AF32) {
#pragma unroll
            for (int c = 0; c < 4; ++c) {
                const float* p = aF + (size_t)(c * 32) * lda + k0;
                rA[2 * c]     = *(const float4*)p;
                rA[2 * c + 1] = *(const float4*)(p + 4);
            }
        } else {
#pragma unroll
            for (int c = 0; c < 4; ++c)
                hA[c] = *(const f16x8*)(aH + (size_t)(c * 32) * lda + k0);
        }
        if constexpr (BF32) {
#pragma unroll
            for (int c = 0; c < 2; ++c) {
                const float* p = bF + (size_t)(c * 32) * ldb + k0;
                rB[2 * c]     = *(const float4*)p;
                rB[2 * c + 1] = *(const float4*)(p + 4);
            }
        } else {
#pragma unroll
            for (int c = 0; c < 2; ++c)
                hB[c] = *(const f16x8*)(bH + (size_t)(c * 32) * ldb + k0);
        }
    };

    auto writeT = [&](int be) {
#pragma unroll
        for (int c = 0; c < 4; ++c) {
            f16x8 v;
            if constexpr (AF32) v = cvt8(rA[2 * c], rA[2 * c + 1]);
            else                v = hA[c];
            *(f16x8*)(lds + be + (c * 32 + rowS) * 64 + slw * 8) = v;
        }
#pragma unroll
        for (int c = 0; c < 2; ++c) {
            f16x8 v;
            if constexpr (BF32) v = cvt8(rB[2 * c], rB[2 * c + 1]);
            else                v = hB[c];
            *(f16x8*)(lds + be + BOF + (c * 32 + rowS) * 64 + slw * 8) = v;
        }
    };

    auto compute = [&](int be) {
#pragma unroll
        for (int w = 0; w < 2; ++w) {
            const int sw = (((w << 2) | fq) ^ (fr & 7)) << 3;
            f16x8 vah[4], vbh[2];
#pragma unroll
            for (int i = 0; i < 4; ++i)
                vah[i] = *(const f16x8*)(lds + be + (wm + i * 16 + fr) * 64 + sw);
#pragma unroll
            for (int j = 0; j < 2; ++j)
                vbh[j] = *(const f16x8*)(lds + be + BOF + (wn + j * 16 + fr) * 64 + sw);
#pragma unroll
            for (int i = 0; i < 4; ++i)
#pragma unroll
                for (int j = 0; j < 2; ++j)
                    acc[i][j] = __builtin_amdgcn_mfma_f32_16x16x32_f16(vah[i], vbh[j], acc[i][j], 0, 0, 0);
        }
    };

    loadT(0);
    writeT(0);
    loadT(64);
    LGKM0_BAR();
    for (int k0 = 0; k0 < K; k0 += 128) {
        compute(0);
        writeT(BUFE);
        if (k0 + 128 < K) loadT(k0 + 128);
        LGKM0_BAR();
        compute(BUFE);
        if (k0 + 128 < K) {
            writeT(0);
            if (k0 + 192 < K) loadT(k0 + 192);
        }
        LGKM0_BAR();
    }

    float bj[2];
    if (BIAS) {
#pragma unroll
        for (int j = 0; j < 2; ++j) bj[j] = bias[n0 + wn + j * 16 + fr];
    }
    const long crow0 = m0 + wm + fq * 4;
    const long ccol0 = n0 + wn + fr;
    float* Cf = (float*)Cv + (size_t)bz * sC;
    u16*   Ch = (u16*)Cv   + (size_t)bz * sC;
    const float* rsb = RS ? (rs + (size_t)bz * 512) : nullptr;
    const int  bzT = (int)(crow0 >> 9);
    const long qb  = crow0 & 511;
#pragma unroll
    for (int i = 0; i < 4; ++i) {
        float rsv[4];
        if (RS) {
#pragma unroll
            for (int r = 0; r < 4; ++r) rsv[r] = 1.0f - rsb[crow0 + i * 16 + r];
        }
#pragma unroll
        for (int j = 0; j < 2; ++j) {
            ushort4 tw;
#pragma unroll
            for (int r = 0; r < 4; ++r) {
                float v = acc[i][j][r];
                if (BIAS) v += RS ? bj[j] * rsv[r] : bj[j];
                if (RELU) v = fmaxf(v, 0.0f);
                const size_t idx = (size_t)(crow0 + i * 16 + r) * ldc + ccol0 + j * 16;
                if (OUT == 0) Cf[idx] = v;
                else {
                    const u16 h = f2h(v);
                    Ch[idx] = h;
                    if (TW) (&tw.x)[r] = h;
                }
            }
            if (OUT == 1 && TW) {
                *(ushort4*)(CT + (size_t)bzT * 768 * 512
                               + (size_t)(ccol0 + j * 16) * 512 + qb + i * 16) = tw;
            }
        }
    }
}

// MedLane masked softmax over 512 (fp32 in), writes fp16 probs in place
// (row stride stays 512 floats = 1024 u16 elements) + rs[row] = S/(S+1e-13).
// 2 reductions: masked entries contribute exactly exp(-M) each to Z, so
//   Z = sve + (512-L)*exp(-M),  S = sve/Z   (analytic; no third reduction).
__global__ __launch_bounds__(256)
void softmax_kernel(float* __restrict__ att, const int* __restrict__ seq_len,
                    float* __restrict__ rsout)
{
    const int row = blockIdx.x;
    const int b   = row >> 9;
    float* s = att + (size_t)row * 512;
    const int L = seq_len[b];
    const int tid = threadIdx.x;

    __shared__ float red[4];

    const float v0 = s[tid];
    const float v1 = s[tid + 256];
    const bool  k0 = (tid < L);
    const bool  k1 = (tid + 256 < L);
    const float s0 = k0 ? v0 : 0.0f;
    const float s1 = k1 ? v1 : 0.0f;

    float m = fmaxf(s0, s1);
#pragma unroll
    for (int o = 32; o > 0; o >>= 1) m = fmaxf(m, __shfl_down(m, o));
    if ((tid & 63) == 0) red[tid >> 6] = m;
    __syncthreads();
    const float M = fmaxf(fmaxf(red[0], red[1]), fmaxf(red[2], red[3]));
    __syncthreads();

    const float e0 = k0 ? expf(s0 - M) : 0.0f;
    const float e1 = k1 ? expf(s1 - M) : 0.0f;

    float zs = e0 + e1;
#pragma unroll
    for (int o = 32; o > 0; o >>= 1) zs += __shfl_down(zs, o);
    if ((tid & 63) == 0) red[tid >> 6] = zs;
    __syncthreads();
    const float sve = red[0] + red[1] + red[2] + red[3];

    const float Z   = sve + (float)(512 - L) * expf(-M);
    const float S   = sve / Z;
    const float inv = 1.0f / (S + 1e-13f);
    const float sc  = inv / Z;

    u16* o16 = (u16*)s;
    o16[tid]       = f2h(k0 ? e0 * sc : 0.0f);
    o16[tid + 256] = f2h(k1 ? e1 * sc : 0.0f);
    if (tid == 0) rsout[row] = S * inv;
}

extern "C" void kernel_launch(void* const* d_in, const int* in_sizes, int n_in,
                              void* d_out, int out_size, void* d_ws, size_t ws_size,
                              hipStream_t stream)
{
    (void)in_sizes; (void)n_in; (void)out_size; (void)ws_size;
    constexpr int B = 16, L = 512, H = 768;
    constexpr size_t NPQ = (size_t)B * L * H;   // 6291456

    const float* proj_p  = (const float*)d_in[0];
    const float* proj_q  = (const float*)d_in[1];
    const int*   seq_len = (const int*)d_in[2];
    const float* W       = (const float*)d_in[3];
    const float* bias    = (const float*)d_in[4];
    float* out = (float*)d_out;

    // workspace (u16 elements): tqT | att | rs   (~29.4 MB of 64)
    u16* ws   = (u16*)d_ws;
    u16* tqT  = ws;                    // [B,768,512] fp16 (trans_q transposed)
    float* att = (float*)(tqT + NPQ);  // [B,512,512] fp32 -> probs fp16 in place
    float* rs  = att + (size_t)B * L * L;  // [B,512] fp32 row sums

    // trans_q fp16 lives in d_out's first half (dead before final GEMM writes)
    u16* tq16 = (u16*)d_out;

    // 1) tq16 = pq @ W^T + bias  (fp32 sources, cvt fused in staging;
    //    fp16 out, dual row-major + transposed write)  grid 12x64 = 768
    gemm_nt<true, true, 1, true, false, false, true, 12, 64><<<768, 256, 0, stream>>>(
        proj_q, W, bias, nullptr, tq16, tqT, H, H, H, H, 0, 0, 0);

    // 2) att[b] = pp[b] @ tq[b]^T  (pp fp32 cvt-fused, tq fp16; fp32 out)
    //    grid 8x4x16 = 512
    gemm_nt<true, false, 0, false, false, false, false, 8, 4><<<512, 256, 0, stream>>>(
        proj_p, tq16, nullptr, nullptr, att, nullptr, H, H, H, L,
        (long)L * H, (long)L * H, (long)L * L);

    // 3) masked softmax (2-reduction), fp16 probs in place + rs
    softmax_kernel<<<B * L, 256, 0, stream>>>(att, seq_len, rs);

    // 4) out = relu(probs @ tqT^T + bias*(1-rs))  grid 12x4x16 = 768
    //    (algebraic fusion: (probs@pq)@W^T + b == probs@tq + b*(1-sum(probs)))
    gemm_nt<false, false, 0, true, true, true, false, 12, 4><<<768, 256, 0, stream>>>(
        (const u16*)att, tqT, bias, rs, out, nullptr,
        L, 1024, L, H, (long)L * 1024, (long)H * L, (long)L * H);
}